// Round 9
// baseline (13.864 us; speedup 1.0000x reference)
//
#include <hip/hip_runtime.h>

// MonotonicityLoss: loss = mean over pairs {same group, galloyl_i > galloyl_j}
// of relu(pred_i - pred_j + MARGIN)^2.
//
// R1: removed 16-byte hipMemsetAsync node (~39us/replay): 45.7 -> 22.8.
// R4: fused per-block group compaction, 2 regular dispatches: 20.45.
// R5: cooperative node costs ~25us. REVERTED.
// R6: leaner main (64x1024, int4 stream, dynamic quarters): 14.37.
// R7: single node via flag/spin finalize: 14.76.
// R8: NSUB=8 (128 blocks): 12.99.
// R9 (this): NSUB=16 (256 blocks, 1/CU). j-partition now DETERMINISTIC by
// original index (separate small j-LDS array) -- removes the cross-block
// compaction-order hazard R6-R8 had. Merged-ballot compaction (1 LDS atomic
// per wave per round), both load rounds issued up-front. One regular node,
// no init, poison/replay-safe.

constexpr int       NG     = 16;          // N_GROUPS
constexpr int       NSUB   = 16;          // j-slices by original index
constexpr int       NBLK   = NG * NSUB;   // 256 blocks (1 per CU)
constexpr int       NT     = 1024;
constexpr int       CAP    = 1024;        // i-array capacity (mean 512, sd ~22)
constexpr int       CAPJ   = 128;         // j-array capacity (mean 32, sd ~5.5)
constexpr float     MARGIN = 0.1f;
constexpr long long MAGIC  = 0x3FC0FFEE5EED5EEDll;

__global__ __launch_bounds__(NT)
void mono_one_kernel(const float* __restrict__ pred,
                     const int*   __restrict__ gall,
                     const int*   __restrict__ grp,
                     int n,
                     double*    __restrict__ part_sum,
                     long long* __restrict__ part_cnt,
                     long long* __restrict__ flags,
                     float*     __restrict__ out)
{
    __shared__ int2   s_i[CAP];          // all group-g elems (any order)
    __shared__ int2   s_j[CAPJ];         // group-g elems in this sub's idx-slice
    __shared__ int    s_cnt, s_jcnt;
    __shared__ double s_ws[NT / 64];
    __shared__ int    s_wc[NT / 64];

    const int tid  = threadIdx.x;
    const int bid  = blockIdx.x;
    const int g    = bid & (NG - 1);     // group
    const int sub  = bid >> 4;           // j-slice index
    const int lane = tid & 63;

    const int jlo = (int)(((long long)sub * n) / NSUB);
    const int jw  = (int)(((long long)(sub + 1) * n) / NSUB) - jlo;

    if (tid == 0) { s_cnt = 0; s_jcnt = 0; }
    __syncthreads();

    // ---- merged-ballot compaction: i = all of group g; j = group g within
    //      original-index slice [jlo, jlo+jw). 1 LDS atomic/wave/round. ----
    auto compact4 = [&](int4 gv, float4 pv, int4 av, int base) {
        const bool c0 = gv.x == g, c1 = gv.y == g, c2 = gv.z == g, c3 = gv.w == g;
        const unsigned long long m0 = __ballot(c0), m1 = __ballot(c1),
                                 m2 = __ballot(c2), m3 = __ballot(c3);
        const int p0 = __popcll(m0), p1 = __popcll(m1), p2 = __popcll(m2);
        int b = 0;
        if (lane == 0) {
            const int t = p0 + p1 + p2 + __popcll(m3);
            if (t) b = atomicAdd(&s_cnt, t);
        }
        b = __shfl(b, 0);
        const unsigned long long below = (1ull << lane) - 1ull;
        if (c0) { const int s = b + __popcll(m0 & below);               if (s < CAP) s_i[s] = make_int2(__float_as_int(pv.x), av.x); }
        if (c1) { const int s = b + p0 + __popcll(m1 & below);          if (s < CAP) s_i[s] = make_int2(__float_as_int(pv.y), av.y); }
        if (c2) { const int s = b + p0 + p1 + __popcll(m2 & below);     if (s < CAP) s_i[s] = make_int2(__float_as_int(pv.z), av.z); }
        if (c3) { const int s = b + p0 + p1 + p2 + __popcll(m3 & below);if (s < CAP) s_i[s] = make_int2(__float_as_int(pv.w), av.w); }

        const bool j0 = c0 && (unsigned)(base + 0 - jlo) < (unsigned)jw;
        const bool j1 = c1 && (unsigned)(base + 1 - jlo) < (unsigned)jw;
        const bool j2 = c2 && (unsigned)(base + 2 - jlo) < (unsigned)jw;
        const bool j3 = c3 && (unsigned)(base + 3 - jlo) < (unsigned)jw;
        const unsigned long long q0 = __ballot(j0), q1 = __ballot(j1),
                                 q2 = __ballot(j2), q3 = __ballot(j3);
        if (q0 | q1 | q2 | q3) {         // wave-uniform; most waves skip
            const int r0 = __popcll(q0), r1 = __popcll(q1), r2 = __popcll(q2);
            int bj = 0;
            if (lane == 0) bj = atomicAdd(&s_jcnt, r0 + r1 + r2 + __popcll(q3));
            bj = __shfl(bj, 0);
            if (j0) { const int s = bj + __popcll(q0 & below);               if (s < CAPJ) s_j[s] = make_int2(__float_as_int(pv.x), av.x); }
            if (j1) { const int s = bj + r0 + __popcll(q1 & below);          if (s < CAPJ) s_j[s] = make_int2(__float_as_int(pv.y), av.y); }
            if (j2) { const int s = bj + r0 + r1 + __popcll(q2 & below);     if (s < CAPJ) s_j[s] = make_int2(__float_as_int(pv.z), av.z); }
            if (j3) { const int s = bj + r0 + r1 + r2 + __popcll(q3 & below);if (s < CAPJ) s_j[s] = make_int2(__float_as_int(pv.w), av.w); }
        }
    };

    if (n == NT * 8) {                   // fast path: both rounds' loads up-front
        const int b0 = tid * 4, b1 = b0 + NT * 4;
        const int4   gv0 = *reinterpret_cast<const int4*>(grp  + b0);
        const int4   gv1 = *reinterpret_cast<const int4*>(grp  + b1);
        const float4 pv0 = *reinterpret_cast<const float4*>(pred + b0);
        const float4 pv1 = *reinterpret_cast<const float4*>(pred + b1);
        const int4   av0 = *reinterpret_cast<const int4*>(gall + b0);
        const int4   av1 = *reinterpret_cast<const int4*>(gall + b1);
        compact4(gv0, pv0, av0, b0);
        compact4(gv1, pv1, av1, b1);
    } else {
        for (int base = tid * 4; base + 3 < n; base += NT * 4) {
            const int4   gv = *reinterpret_cast<const int4*>(grp  + base);
            const float4 pv = *reinterpret_cast<const float4*>(pred + base);
            const int4   av = *reinterpret_cast<const int4*>(gall + base);
            compact4(gv, pv, av, base);
        }
        for (int idx = (n & ~3) + tid; idx < n; idx += NT) {   // scalar tail
            if (grp[idx] == g) {
                const int2 v = make_int2(__float_as_int(pred[idx]), gall[idx]);
                const int s = atomicAdd(&s_cnt, 1);
                if (s < CAP) s_i[s] = v;
                if ((unsigned)(idx - jlo) < (unsigned)jw) {
                    const int sj = atomicAdd(&s_jcnt, 1);
                    if (sj < CAPJ) s_j[sj] = v;
                }
            }
        }
    }
    __syncthreads();

    const int size = min(s_cnt, CAP);
    const int jn   = min(s_jcnt, CAPJ);

    // ---- per-thread i, loop over this block's j-slice ----
    float pim = 0.0f;
    int   gi  = -1;                      // sentinel: never > gall_j (>=0)
    if (tid < size) {
        const int2 v = s_i[tid];
        pim = __int_as_float(v.x) + MARGIN;
        gi  = v.y;
    }

    float vsum = 0.0f;
    int   vcnt = 0;
    if ((int)(tid & ~63u) < size) {      // wave-uniform skip of empty i-waves
        for (int t = 0; t < jn; ++t) {
            const int2  v = s_j[t];      // uniform addr -> LDS broadcast
            const bool  m = gi > v.y;
            const float d = pim - __int_as_float(v.x);
            float       r = fmaxf(d, 0.0f);
            r = m ? r : 0.0f;
            vsum = fmaf(r, r, vsum);
            vcnt += (int)m;
        }
    }

    // ---- wave (64) + block reduction -> this block's partial slot ----
    double w = (double)vsum;
    int    c = vcnt;
    for (int off = 32; off > 0; off >>= 1) {
        w += __shfl_down(w, off);
        c += __shfl_down(c, off);
    }
    if ((tid & 63) == 0) { s_ws[tid >> 6] = w; s_wc[tid >> 6] = c; }
    __syncthreads();
    if (tid == 0) {
        double    bs = 0.0;
        long long bc = 0;
        #pragma unroll
        for (int wv = 0; wv < NT / 64; ++wv) { bs += s_ws[wv]; bc += (long long)s_wc[wv]; }
        __hip_atomic_store(&part_sum[bid], bs, __ATOMIC_RELAXED, __HIP_MEMORY_SCOPE_AGENT);
        __hip_atomic_store(&part_cnt[bid], bc, __ATOMIC_RELAXED, __HIP_MEMORY_SCOPE_AGENT);
        __hip_atomic_store(&flags[bid], MAGIC, __ATOMIC_RELEASE, __HIP_MEMORY_SCOPE_AGENT);
    }

    // ---- block 0, wave 0: spin on all 256 flags (4/lane), then finalize ----
    if (bid == 0 && tid < 64) {
        bool done = false;
        while (!done) {
            done = true;
            #pragma unroll
            for (int k = 0; k < NBLK / 64; ++k)
                done &= (__hip_atomic_load(&flags[tid + 64 * k], __ATOMIC_ACQUIRE,
                                           __HIP_MEMORY_SCOPE_AGENT) == MAGIC);
            if (!done) __builtin_amdgcn_s_sleep(1);
        }
        double    ts = 0.0;
        long long tc = 0;
        #pragma unroll
        for (int k = 0; k < NBLK / 64; ++k) {
            ts += __hip_atomic_load(&part_sum[tid + 64 * k], __ATOMIC_RELAXED,
                                    __HIP_MEMORY_SCOPE_AGENT);
            tc += __hip_atomic_load(&part_cnt[tid + 64 * k], __ATOMIC_RELAXED,
                                    __HIP_MEMORY_SCOPE_AGENT);
        }
        for (int off = 32; off > 0; off >>= 1) {
            ts += __shfl_down(ts, off);
            tc += __shfl_down(tc, off);
        }
        if (tid == 0)
            out[0] = (tc > 0) ? (float)(ts / (double)tc) : 0.0f;
    }
}

extern "C" void kernel_launch(void* const* d_in, const int* in_sizes, int n_in,
                              void* d_out, int out_size, void* d_ws, size_t ws_size,
                              hipStream_t stream)
{
    const float* pred = (const float*)d_in[0];
    const int*   gall = (const int*)d_in[1];
    const int*   grp  = (const int*)d_in[2];
    const int    n    = in_sizes[0];

    char* ws = (char*)d_ws;
    double*    part_sum = (double*)ws;                                    // 2 KB
    long long* part_cnt = (long long*)(ws + NBLK * sizeof(double));       // 2 KB
    long long* flags    = (long long*)(ws + 2 * NBLK * sizeof(double));   // 2 KB

    mono_one_kernel<<<NBLK, NT, 0, stream>>>(pred, gall, grp, n,
                                             part_sum, part_cnt, flags,
                                             (float*)d_out);
}

// Round 10
// 13.659 us; speedup vs baseline: 1.0151x; 1.0151x over previous
//
#include <hip/hip_runtime.h>

// MonotonicityLoss: loss = mean over pairs {same group, galloyl_i > galloyl_j}
// of relu(pred_i - pred_j + MARGIN)^2.
//
// R1: removed 16-byte hipMemsetAsync node (~39us/replay): 45.7 -> 22.8.
// R4: fused per-block group compaction, 2 regular dispatches: 20.45.
// R5: cooperative node costs ~25us. REVERTED.
// R6: leaner main (64x1024, int4 stream, dynamic quarters): 14.37.
// R7: single node via flag/spin finalize: 14.76.
// R8: NSUB=8 (128 blocks): 12.99 (but j-partition had an order hazard).
// R9: NSUB=16 + deterministic j via dual compaction: 13.86 (compaction 2x).
// R10 (this): index-compaction. Stream ONLY grp (32KB/block, not 96KB),
// ballot-compact member INDICES; pred/gall gathered per-thread from L2 into
// registers; j-set = members with original index in this block's slice (a
// SET -> order-independent, hazard stays fixed), built by one ballot round
// from registers. 256 blocks (1/CU), 32-iter pair loop. One regular node,
// no init, poison/replay-safe.

constexpr int       NG     = 16;          // N_GROUPS
constexpr int       NSUB   = 16;          // j-slices by original index
constexpr int       NBLK   = NG * NSUB;   // 256 blocks (1 per CU)
constexpr int       NT     = 1024;
constexpr int       CAP    = 1024;        // member-index capacity (mean 512)
constexpr int       CAPJ   = 128;         // j capacity (mean 32, sd ~5.6)
constexpr float     MARGIN = 0.1f;
constexpr long long MAGIC  = 0x3FC0FFEE5EED5EEDll;

__global__ __launch_bounds__(NT)
void mono_one_kernel(const float* __restrict__ pred,
                     const int*   __restrict__ gall,
                     const int*   __restrict__ grp,
                     int n,
                     double*    __restrict__ part_sum,
                     long long* __restrict__ part_cnt,
                     long long* __restrict__ flags,
                     float*     __restrict__ out)
{
    __shared__ int    s_idx[CAP];        // original indices of group-g members
    __shared__ int2   s_j[CAPJ];         // (pred bits, gall) of j-slice members
    __shared__ int    s_cnt, s_jcnt;
    __shared__ double s_ws[NT / 64];
    __shared__ int    s_wc[NT / 64];

    const int tid  = threadIdx.x;
    const int bid  = blockIdx.x;
    const int g    = bid & (NG - 1);     // group
    const int sub  = bid >> 4;           // j-slice index
    const int lane = tid & 63;

    const int jlo = (int)(((long long)sub * n) / NSUB);
    const int jhi = (int)(((long long)(sub + 1) * n) / NSUB);

    if (tid == 0) { s_cnt = 0; s_jcnt = 0; }
    __syncthreads();

    // ---- phase 1: compact member indices (stream grp only, int4) ----
    auto compactIdx = [&](int4 gv, int base) {
        const bool c0 = gv.x == g, c1 = gv.y == g, c2 = gv.z == g, c3 = gv.w == g;
        const unsigned long long m0 = __ballot(c0), m1 = __ballot(c1),
                                 m2 = __ballot(c2), m3 = __ballot(c3);
        const int p0 = __popcll(m0), p1 = __popcll(m1), p2 = __popcll(m2);
        int b = 0;
        if (lane == 0) {
            const int t = p0 + p1 + p2 + __popcll(m3);
            if (t) b = atomicAdd(&s_cnt, t);
        }
        b = __shfl(b, 0);
        const unsigned long long below = (1ull << lane) - 1ull;
        if (c0) { const int s = b + __popcll(m0 & below);                if (s < CAP) s_idx[s] = base + 0; }
        if (c1) { const int s = b + p0 + __popcll(m1 & below);           if (s < CAP) s_idx[s] = base + 1; }
        if (c2) { const int s = b + p0 + p1 + __popcll(m2 & below);      if (s < CAP) s_idx[s] = base + 2; }
        if (c3) { const int s = b + p0 + p1 + p2 + __popcll(m3 & below); if (s < CAP) s_idx[s] = base + 3; }
    };

    if (n == NT * 8) {                   // fast path: both rounds' loads up-front
        const int b0 = tid * 4, b1 = b0 + NT * 4;
        const int4 gv0 = *reinterpret_cast<const int4*>(grp + b0);
        const int4 gv1 = *reinterpret_cast<const int4*>(grp + b1);
        compactIdx(gv0, b0);
        compactIdx(gv1, b1);
    } else {
        for (int base = tid * 4; base + 3 < n; base += NT * 4)
            compactIdx(*reinterpret_cast<const int4*>(grp + base), base);
        for (int idx = (n & ~3) + tid; idx < n; idx += NT)     // scalar tail
            if (grp[idx] == g) {
                const int s = atomicAdd(&s_cnt, 1);
                if (s < CAP) s_idx[s] = idx;
            }
    }
    __syncthreads();

    const int size = min(s_cnt, CAP);

    // ---- phase 2: per-thread register gather of (pred, gall) from L2 ----
    float pj  = 0.0f;                    // raw pred_i (for j staging)
    float pim = 0.0f;                    // pred_i + margin (for i role)
    int   gi  = -1;                      // sentinel: never > gall_j (>=0)
    int   myidx = -1;
    if (tid < size) {
        myidx = s_idx[tid];
        pj    = pred[myidx];
        gi    = gall[myidx];
        pim   = pj + MARGIN;
    }

    // ---- build j-array: members whose ORIGINAL index is in [jlo, jhi).
    //      Set membership is order-independent -> deterministic partition. ----
    {
        const bool c = (myidx >= jlo) & (myidx < jhi);   // myidx=-1 -> false
        const unsigned long long m = __ballot(c);
        if (m) {                        // wave-uniform skip
            int b = 0;
            if (lane == 0) b = atomicAdd(&s_jcnt, __popcll(m));
            b = __shfl(b, 0);
            if (c) {
                const int s = b + __popcll(m & ((1ull << lane) - 1ull));
                if (s < CAPJ) s_j[s] = make_int2(__float_as_int(pj), gi);
            }
        }
    }
    __syncthreads();

    const int jn = min(s_jcnt, CAPJ);

    // ---- pair loop: every i vs this block's j-slice (~32 iters) ----
    float vsum = 0.0f;
    int   vcnt = 0;
    if ((int)(tid & ~63u) < size) {      // wave-uniform skip of empty i-waves
        for (int t = 0; t < jn; ++t) {
            const int2  v = s_j[t];      // uniform addr -> LDS broadcast
            const bool  m = gi > v.y;
            const float d = pim - __int_as_float(v.x);
            float       r = fmaxf(d, 0.0f);
            r = m ? r : 0.0f;
            vsum = fmaf(r, r, vsum);
            vcnt += (int)m;
        }
    }

    // ---- wave (64) + block reduction -> this block's partial slot ----
    double w = (double)vsum;
    int    c = vcnt;
    for (int off = 32; off > 0; off >>= 1) {
        w += __shfl_down(w, off);
        c += __shfl_down(c, off);
    }
    if ((tid & 63) == 0) { s_ws[tid >> 6] = w; s_wc[tid >> 6] = c; }
    __syncthreads();
    if (tid == 0) {
        double    bs = 0.0;
        long long bc = 0;
        #pragma unroll
        for (int wv = 0; wv < NT / 64; ++wv) { bs += s_ws[wv]; bc += (long long)s_wc[wv]; }
        __hip_atomic_store(&part_sum[bid], bs, __ATOMIC_RELAXED, __HIP_MEMORY_SCOPE_AGENT);
        __hip_atomic_store(&part_cnt[bid], bc, __ATOMIC_RELAXED, __HIP_MEMORY_SCOPE_AGENT);
        __hip_atomic_store(&flags[bid], MAGIC, __ATOMIC_RELEASE, __HIP_MEMORY_SCOPE_AGENT);
    }

    // ---- block 0, wave 0: spin on all 256 flags (4/lane), then finalize ----
    if (bid == 0 && tid < 64) {
        bool done = false;
        while (!done) {
            done = true;
            #pragma unroll
            for (int k = 0; k < NBLK / 64; ++k)
                done &= (__hip_atomic_load(&flags[tid + 64 * k], __ATOMIC_ACQUIRE,
                                           __HIP_MEMORY_SCOPE_AGENT) == MAGIC);
            if (!done) __builtin_amdgcn_s_sleep(1);
        }
        double    ts = 0.0;
        long long tc = 0;
        #pragma unroll
        for (int k = 0; k < NBLK / 64; ++k) {
            ts += __hip_atomic_load(&part_sum[tid + 64 * k], __ATOMIC_RELAXED,
                                    __HIP_MEMORY_SCOPE_AGENT);
            tc += __hip_atomic_load(&part_cnt[tid + 64 * k], __ATOMIC_RELAXED,
                                    __HIP_MEMORY_SCOPE_AGENT);
        }
        for (int off = 32; off > 0; off >>= 1) {
            ts += __shfl_down(ts, off);
            tc += __shfl_down(tc, off);
        }
        if (tid == 0)
            out[0] = (tc > 0) ? (float)(ts / (double)tc) : 0.0f;
    }
}

extern "C" void kernel_launch(void* const* d_in, const int* in_sizes, int n_in,
                              void* d_out, int out_size, void* d_ws, size_t ws_size,
                              hipStream_t stream)
{
    const float* pred = (const float*)d_in[0];
    const int*   gall = (const int*)d_in[1];
    const int*   grp  = (const int*)d_in[2];
    const int    n    = in_sizes[0];

    char* ws = (char*)d_ws;
    double*    part_sum = (double*)ws;                                    // 2 KB
    long long* part_cnt = (long long*)(ws + NBLK * sizeof(double));       // 2 KB
    long long* flags    = (long long*)(ws + 2 * NBLK * sizeof(double));   // 2 KB

    mono_one_kernel<<<NBLK, NT, 0, stream>>>(pred, gall, grp, n,
                                             part_sum, part_cnt, flags,
                                             (float*)d_out);
}

// Round 11
// 12.843 us; speedup vs baseline: 1.0795x; 1.0635x over previous
//
#include <hip/hip_runtime.h>

// MonotonicityLoss: loss = mean over pairs {same group, galloyl_i > galloyl_j}
// of relu(pred_i - pred_j + MARGIN)^2.
//
// R1:  removed 16-byte hipMemsetAsync node (~39us/replay): 45.7 -> 22.8.
// R4:  fused per-block group compaction, 2 regular dispatches: 20.45.
// R5:  cooperative node costs ~25us. REVERTED.
// R6:  64x1024, int4 stream, dynamic quarters: 14.37.
// R7:  single node via flag/spin finalize: 14.76.
// R8:  NSUB=8 (128 blocks): 12.99 -- best, but j-partition raced on
//      per-block compaction order.
// R9:  256 blocks + dual compaction: 13.86 (2x blocks/stream cost).
// R10: 256 blocks + grp-only stream + scattered gather: 13.66 (uncoalesced).
// R11 (this): R8 geometry (128 blocks, coalesced full stream, 64-iter pair
// loop) + DETERMINISTIC j-array: second ballot-compaction keyed on the
// element's ORIGINAL index slice (pure function of element -> order-free),
// built from the same registers in the same pass (~50 extra cycles).
// One regular node, no init, poison/replay-safe.

constexpr int       NG     = 16;          // N_GROUPS
constexpr int       NSUB   = 8;           // j-slices by original index
constexpr int       NBLK   = NG * NSUB;   // 128 blocks (all co-resident)
constexpr int       NT     = 1024;
constexpr int       CAP    = 1024;        // i capacity (group mean 512, sd ~22)
constexpr int       CAPJ   = 160;         // j capacity (mean 64, sd ~7.7)
constexpr float     MARGIN = 0.1f;
constexpr long long MAGIC  = 0x3FC0FFEE5EED5EEDll;

__global__ __launch_bounds__(NT)
void mono_one_kernel(const float* __restrict__ pred,
                     const int*   __restrict__ gall,
                     const int*   __restrict__ grp,
                     int n,
                     double*    __restrict__ part_sum,
                     long long* __restrict__ part_cnt,
                     long long* __restrict__ flags,
                     float*     __restrict__ out)
{
    __shared__ int2   s_i[CAP];          // all group-g elems (order arbitrary)
    __shared__ int2   s_j[CAPJ];         // group-g elems in this idx-slice
    __shared__ int    s_cnt, s_jcnt;
    __shared__ double s_ws[NT / 64];
    __shared__ int    s_wc[NT / 64];

    const int tid  = threadIdx.x;
    const int bid  = blockIdx.x;
    const int g    = bid & (NG - 1);     // group
    const int sub  = bid >> 4;           // j-slice index
    const int lane = tid & 63;

    const int jlo = (int)(((long long)sub * n) / NSUB);
    const int jhi = (int)(((long long)(sub + 1) * n) / NSUB);

    if (tid == 0) { s_cnt = 0; s_jcnt = 0; }
    __syncthreads();

    // ---- one coalesced pass: i-compaction (all of group g) + deterministic
    //      j-compaction (group g AND original idx in [jlo,jhi)). ----
    auto compact4 = [&](int4 gv, float4 pv, int4 av, int base) {
        const bool c0 = gv.x == g, c1 = gv.y == g, c2 = gv.z == g, c3 = gv.w == g;
        const unsigned long long m0 = __ballot(c0), m1 = __ballot(c1),
                                 m2 = __ballot(c2), m3 = __ballot(c3);
        const int p0 = __popcll(m0), p1 = __popcll(m1), p2 = __popcll(m2);
        int b = 0;
        if (lane == 0) {
            const int t = p0 + p1 + p2 + __popcll(m3);
            if (t) b = atomicAdd(&s_cnt, t);
        }
        b = __shfl(b, 0);
        const unsigned long long below = (1ull << lane) - 1ull;
        if (c0) { const int s = b + __popcll(m0 & below);                if (s < CAP) s_i[s] = make_int2(__float_as_int(pv.x), av.x); }
        if (c1) { const int s = b + p0 + __popcll(m1 & below);           if (s < CAP) s_i[s] = make_int2(__float_as_int(pv.y), av.y); }
        if (c2) { const int s = b + p0 + p1 + __popcll(m2 & below);      if (s < CAP) s_i[s] = make_int2(__float_as_int(pv.z), av.z); }
        if (c3) { const int s = b + p0 + p1 + p2 + __popcll(m3 & below); if (s < CAP) s_i[s] = make_int2(__float_as_int(pv.w), av.w); }

        // deterministic j-subset: pure function of (grp, original idx)
        const bool j0 = c0 && (unsigned)(base + 0 - jlo) < (unsigned)(jhi - jlo);
        const bool j1 = c1 && (unsigned)(base + 1 - jlo) < (unsigned)(jhi - jlo);
        const bool j2 = c2 && (unsigned)(base + 2 - jlo) < (unsigned)(jhi - jlo);
        const bool j3 = c3 && (unsigned)(base + 3 - jlo) < (unsigned)(jhi - jlo);
        const unsigned long long q0 = __ballot(j0), q1 = __ballot(j1),
                                 q2 = __ballot(j2), q3 = __ballot(j3);
        if (q0 | q1 | q2 | q3) {         // wave-uniform; 7/8 of waves skip
            const int r0 = __popcll(q0), r1 = __popcll(q1), r2 = __popcll(q2);
            int bj = 0;
            if (lane == 0) bj = atomicAdd(&s_jcnt, r0 + r1 + r2 + __popcll(q3));
            bj = __shfl(bj, 0);
            if (j0) { const int s = bj + __popcll(q0 & below);                if (s < CAPJ) s_j[s] = make_int2(__float_as_int(pv.x), av.x); }
            if (j1) { const int s = bj + r0 + __popcll(q1 & below);           if (s < CAPJ) s_j[s] = make_int2(__float_as_int(pv.y), av.y); }
            if (j2) { const int s = bj + r0 + r1 + __popcll(q2 & below);      if (s < CAPJ) s_j[s] = make_int2(__float_as_int(pv.z), av.z); }
            if (j3) { const int s = bj + r0 + r1 + r2 + __popcll(q3 & below); if (s < CAPJ) s_j[s] = make_int2(__float_as_int(pv.w), av.w); }
        }
    };

    if (n == NT * 8) {                   // fast path: both rounds' loads up-front
        const int b0 = tid * 4, b1 = b0 + NT * 4;
        const int4   gv0 = *reinterpret_cast<const int4*>(grp  + b0);
        const int4   gv1 = *reinterpret_cast<const int4*>(grp  + b1);
        const float4 pv0 = *reinterpret_cast<const float4*>(pred + b0);
        const float4 pv1 = *reinterpret_cast<const float4*>(pred + b1);
        const int4   av0 = *reinterpret_cast<const int4*>(gall + b0);
        const int4   av1 = *reinterpret_cast<const int4*>(gall + b1);
        compact4(gv0, pv0, av0, b0);
        compact4(gv1, pv1, av1, b1);
    } else {
        for (int base = tid * 4; base + 3 < n; base += NT * 4) {
            const int4   gv = *reinterpret_cast<const int4*>(grp  + base);
            const float4 pv = *reinterpret_cast<const float4*>(pred + base);
            const int4   av = *reinterpret_cast<const int4*>(gall + base);
            compact4(gv, pv, av, base);
        }
        for (int idx = (n & ~3) + tid; idx < n; idx += NT) {   // scalar tail
            if (grp[idx] == g) {
                const int2 v = make_int2(__float_as_int(pred[idx]), gall[idx]);
                const int s = atomicAdd(&s_cnt, 1);
                if (s < CAP) s_i[s] = v;
                if (idx >= jlo && idx < jhi) {
                    const int sj = atomicAdd(&s_jcnt, 1);
                    if (sj < CAPJ) s_j[sj] = v;
                }
            }
        }
    }
    __syncthreads();

    const int size = min(s_cnt, CAP);
    const int jn   = min(s_jcnt, CAPJ);

    // ---- per-thread i vs this block's j-slice (~64 iters) ----
    float pim = 0.0f;
    int   gi  = -1;                      // sentinel: never > gall_j (>=0)
    if (tid < size) {
        const int2 v = s_i[tid];
        pim = __int_as_float(v.x) + MARGIN;
        gi  = v.y;
    }

    float vsum = 0.0f;
    int   vcnt = 0;
    if ((int)(tid & ~63u) < size) {      // wave-uniform skip of empty i-waves
        for (int t = 0; t < jn; ++t) {
            const int2  v = s_j[t];      // uniform addr -> LDS broadcast
            const bool  m = gi > v.y;
            const float d = pim - __int_as_float(v.x);
            float       r = fmaxf(d, 0.0f);
            r = m ? r : 0.0f;
            vsum = fmaf(r, r, vsum);
            vcnt += (int)m;
        }
    }

    // ---- wave (64) + block reduction -> this block's partial slot ----
    double w = (double)vsum;
    int    c = vcnt;
    for (int off = 32; off > 0; off >>= 1) {
        w += __shfl_down(w, off);
        c += __shfl_down(c, off);
    }
    if ((tid & 63) == 0) { s_ws[tid >> 6] = w; s_wc[tid >> 6] = c; }
    __syncthreads();
    if (tid == 0) {
        double    bs = 0.0;
        long long bc = 0;
        #pragma unroll
        for (int wv = 0; wv < NT / 64; ++wv) { bs += s_ws[wv]; bc += (long long)s_wc[wv]; }
        __hip_atomic_store(&part_sum[bid], bs, __ATOMIC_RELAXED, __HIP_MEMORY_SCOPE_AGENT);
        __hip_atomic_store(&part_cnt[bid], bc, __ATOMIC_RELAXED, __HIP_MEMORY_SCOPE_AGENT);
        __hip_atomic_store(&flags[bid], MAGIC, __ATOMIC_RELEASE, __HIP_MEMORY_SCOPE_AGENT);
    }

    // ---- block 0, wave 0: spin on all 128 flags (2/lane), then finalize ----
    if (bid == 0 && tid < 64) {
        bool done = false;
        while (!done) {
            done = true;
            #pragma unroll
            for (int k = 0; k < NBLK / 64; ++k)
                done &= (__hip_atomic_load(&flags[tid + 64 * k], __ATOMIC_ACQUIRE,
                                           __HIP_MEMORY_SCOPE_AGENT) == MAGIC);
            if (!done) __builtin_amdgcn_s_sleep(1);
        }
        double    ts = 0.0;
        long long tc = 0;
        #pragma unroll
        for (int k = 0; k < NBLK / 64; ++k) {
            ts += __hip_atomic_load(&part_sum[tid + 64 * k], __ATOMIC_RELAXED,
                                    __HIP_MEMORY_SCOPE_AGENT);
            tc += __hip_atomic_load(&part_cnt[tid + 64 * k], __ATOMIC_RELAXED,
                                    __HIP_MEMORY_SCOPE_AGENT);
        }
        for (int off = 32; off > 0; off >>= 1) {
            ts += __shfl_down(ts, off);
            tc += __shfl_down(tc, off);
        }
        if (tid == 0)
            out[0] = (tc > 0) ? (float)(ts / (double)tc) : 0.0f;
    }
}

extern "C" void kernel_launch(void* const* d_in, const int* in_sizes, int n_in,
                              void* d_out, int out_size, void* d_ws, size_t ws_size,
                              hipStream_t stream)
{
    const float* pred = (const float*)d_in[0];
    const int*   gall = (const int*)d_in[1];
    const int*   grp  = (const int*)d_in[2];
    const int    n    = in_sizes[0];

    char* ws = (char*)d_ws;
    double*    part_sum = (double*)ws;                                    // 1 KB
    long long* part_cnt = (long long*)(ws + NBLK * sizeof(double));       // 1 KB
    long long* flags    = (long long*)(ws + 2 * NBLK * sizeof(double));   // 1 KB

    mono_one_kernel<<<NBLK, NT, 0, stream>>>(pred, gall, grp, n,
                                             part_sum, part_cnt, flags,
                                             (float*)d_out);
}